// Round 1
// baseline (116.086 us; speedup 1.0000x reference)
//
#include <hip/hip_runtime.h>
#include <hip/hip_bf16.h>
#include <math.h>

// Problem constants (B=1)
#define TT   512
#define CEMB 768
#define NH   12
#define NKV  6
#define HD   64
#define KVC  (NKV*HD)   // 384

typedef short short8 __attribute__((ext_vector_type(8)));
typedef float floatx4 __attribute__((ext_vector_type(4)));
typedef float floatx2 __attribute__((ext_vector_type(2)));

// fp32 pair -> packed bf16 (round-to-nearest via HW packed convert)
__device__ __forceinline__ unsigned pack_bf16(float lo, float hi){
  __hip_bfloat162 h = __float22bfloat162_rn(make_float2(lo, hi));
  return *reinterpret_cast<unsigned*>(&h);
}
__device__ __forceinline__ unsigned short bf16_rn(float f){
  unsigned u = __float_as_uint(f);
  u += 0x7FFFu + ((u>>16)&1u);
  return (unsigned short)(u>>16);
}
__device__ __forceinline__ float bf16_to_f32(unsigned short u){
  return __uint_as_float(((unsigned)u) << 16);
}

// ============================================================================
// K1: QKV GEMM via bf16 MFMA + block-local RoPE/RMS epilogue.
// Grid x: 0..191 = gemm tiles, 192..227 = Wp fragment-pack blocks.
// Round-13 change: 2-deep register prefetch (load k+64 while packing k) so
// the global-load latency is covered by a full K-iteration, not just sync+MFMA.
// ============================================================================
__global__ void __launch_bounds__(256) gemm_qkv_mfma(
    const float* __restrict__ X,
    const float* __restrict__ Wq, const float* __restrict__ Wk, const float* __restrict__ Wv,
    const float* __restrict__ Wp,
    const float* __restrict__ cosb, const float* __restrict__ sinb,
    float* __restrict__ q, float* __restrict__ k, float* __restrict__ v,
    unsigned short* __restrict__ WpF){
  int bx = blockIdx.x;
  if (bx >= 192){
    int t0 = (bx-192)*256 + threadIdx.x;           // 0..9215
    for(int g=0; g<8; ++g){
      int u  = g*9216 + t0;                        // 0..73727
      int kp = u / 192;
      int n4 = (u - kp*192)*4;
      int kk = kp*2;
      float4 w0 = *(const float4*)&Wp[(size_t)kk*CEMB + n4];
      float4 w1 = *(const float4*)&Wp[(size_t)(kk+1)*CEMB + n4];
      int ks = kk>>5, qq = (kk>>3)&3, j = kk&7;    // j even
      #pragma unroll
      for(int i=0;i<4;i++){
        int n = n4+i, ct = n>>4, r = n&15;
        *(unsigned*)&WpF[ (((size_t)(ct*24 + ks)*64 + qq*16 + r)<<3) + j ] =
          pack_bf16((&w0.x)[i], (&w1.x)[i]);
      }
    }
    return;
  }
  int mt = bx / 24, nt = bx % 24;
  const float* W; int ldb, bcol;
  if (nt < 12)      { W = Wq; ldb = CEMB; bcol = nt*64; }
  else if (nt < 18) { W = Wk; ldb = KVC;  bcol = (nt-12)*64; }
  else              { W = Wv; ldb = KVC;  bcol = (nt-18)*64; }

  __shared__ __align__(16) unsigned short Al[2][64][40];
  __shared__ __align__(16) unsigned short Bl[2][64][40];

  int tid = threadIdx.x;
  int am  = tid>>2,  akg = (tid&3)*8;
  int bkp = tid>>4,  bn4 = (tid&15)*4;
  int w = tid>>6, lane = tid&63, qq = lane>>4, r = lane&15;

  floatx4 acc[4];
  #pragma unroll
  for(int c=0;c<4;c++) acc[c] = (floatx4){0.f,0.f,0.f,0.f};

  const float* Ap = X + (size_t)(mt*64 + am)*CEMB + akg;
  const float* Bp = W + (size_t)(2*bkp)*ldb + bcol + bn4;

  // two independent register sets: set0 holds k0%64==0 tiles, set1 k0%64==32
  float4 a00 = *(const float4*)(Ap);
  float4 a01 = *(const float4*)(Ap + 4);
  float4 b00 = *(const float4*)(Bp);
  float4 b01 = *(const float4*)(Bp + ldb);
  float4 a10 = *(const float4*)(Ap + 32);
  float4 a11 = *(const float4*)(Ap + 36);
  float4 b10 = *(const float4*)(Bp + (size_t)32*ldb);
  float4 b11 = *(const float4*)(Bp + (size_t)33*ldb);

  auto step = [&](int k0, float4& A0, float4& A1, float4& B0, float4& B1,
                  int bufc) {
    unsigned p0 = pack_bf16(A0.x,A0.y), p1 = pack_bf16(A0.z,A0.w);
    unsigned p2 = pack_bf16(A1.x,A1.y), p3 = pack_bf16(A1.z,A1.w);
    *(uint4*)&Al[bufc][am][akg] = make_uint4(p0,p1,p2,p3);
    #pragma unroll
    for(int i=0;i<4;i++)
      *(unsigned*)&Bl[bufc][bn4+i][2*bkp] = pack_bf16((&B0.x)[i], (&B1.x)[i]);
    if (k0 + 64 < CEMB){                 // prefetch 2 steps ahead
      A0 = *(const float4*)(Ap + k0+64);
      A1 = *(const float4*)(Ap + k0+68);
      B0 = *(const float4*)(Bp + (size_t)(k0+64)*ldb);
      B1 = *(const float4*)(Bp + (size_t)(k0+65)*ldb);
    }
    __syncthreads();
    short8 af = *(short8*)&Al[bufc][w*16 + r][qq*8];
    #pragma unroll
    for(int c=0;c<4;c++){
      short8 bfr = *(short8*)&Bl[bufc][c*16 + r][qq*8];
      acc[c] = __builtin_amdgcn_mfma_f32_16x16x32_bf16(af, bfr, acc[c], 0,0,0);
    }
  };

  for(int k0=0; k0<CEMB; k0+=64){
    step(k0,    a00,a01,b00,b01, 0);
    step(k0+32, a10,a11,b10,b11, 1);
  }

  // epilogue: RoPE pairs d<->d+32 = acc c<->c+2 (same lane); RMS over 16 lanes.
  #pragma unroll
  for(int reg=0; reg<4; ++reg){
    int t = mt*64 + w*16 + qq*4 + reg;
    if (nt < 18){
      float cs0 = cosb[t*32 + r],      sn0 = sinb[t*32 + r];
      float cs1 = cosb[t*32 + 16 + r], sn1 = sinb[t*32 + 16 + r];
      float x0 = acc[0][reg], x1 = acc[1][reg], x2 = acc[2][reg], x3 = acc[3][reg];
      float n0 = x0*cs0 - x2*sn0;
      float n1 = x1*cs1 - x3*sn1;
      float n2 = x2*cs0 + x0*sn0;
      float n3 = x3*cs1 + x1*sn1;
      float ss = n0*n0 + n1*n1 + n2*n2 + n3*n3;
      ss += __shfl_xor(ss,1); ss += __shfl_xor(ss,2);
      ss += __shfl_xor(ss,4); ss += __shfl_xor(ss,8);
      float sc = rsqrtf(ss*(1.0f/64.0f) + 1e-6f);
      float* dst = (nt < 12) ? (q + (size_t)t*CEMB + nt*64)
                             : (k + (size_t)t*KVC + (nt-12)*64);
      dst[r]    = n0*sc; dst[16+r] = n1*sc;
      dst[32+r] = n2*sc; dst[48+r] = n3*sc;
    } else {
      float* dst = v + (size_t)t*KVC + (nt-18)*64;
      dst[r]    = acc[0][reg]; dst[16+r] = acc[1][reg];
      dst[32+r] = acc[2][reg]; dst[48+r] = acc[3][reg];
    }
  }
}

// ============================================================================
// K2: tropical attention. Round-13 changes:
//  - Q-strip split 64 -> 32 rows: 72 tiles/head = 864 blocks (1.7 -> 3.4
//    blocks/CU, ~3-4 waves/SIMD) for latency hiding; chunk layout (ct 0..7)
//    unchanged so K3 is untouched.
//  - inner loops on float2 ext-vectors so LLVM selects v_pk_add_f32 /
//    v_pk_fma_f32: max-plus step 8 -> ~5 ops, PV FMA count halved.
// ============================================================================
__global__ void __launch_bounds__(256) attn_tile(const float* __restrict__ qn,
    const float* __restrict__ kn, const float* __restrict__ vr,
    unsigned short* __restrict__ part_acc, float2* __restrict__ part_ml){
  __shared__ float QPsh[32*68];
  __shared__ float Ksh[64*64];
  __shared__ float Vsh[64*64];

  int h   = blockIdx.y;
  int idx = blockIdx.x;          // 0..71
  int qs = 0, rem = idx;         // strip qs has (qs>>1)+1 causal KV chunks
  while (rem > (qs>>1)){ rem -= (qs>>1)+1; ++qs; }
  int ct = rem;                  // 0..qs>>1
  int t0 = ct*64;

  int kvh  = h >> 1;
  int tid  = threadIdx.x;
  int w    = tid >> 6;
  int lane = tid & 63;
  int lg   = lane >> 4;
  int lc   = lane & 15;

  // Q strip: 32 rows x 64 dims, stride-68 (also reused for P)
  {
    int rr = tid >> 4;           // 0..15
    int c4 = (tid & 15) * 4;
    *(float4*)&QPsh[rr*68 + c4] =
      *(const float4*)&qn[(size_t)(qs*32+rr)*CEMB + h*HD + c4];
    *(float4*)&QPsh[(rr+16)*68 + c4] =
      *(const float4*)&qn[(size_t)(qs*32+rr+16)*CEMB + h*HD + c4];
  }
  // K/V tiles: 64 rows x 64 dims, XOR-swizzled columns
  #pragma unroll
  for(int sub=0; sub<4; ++sub){
    int rr = w*16 + sub*4 + lg;
    int sw = ((lc ^ (rr>>2)) & 15)*4;
    *(float4*)&Ksh[rr*64 + sw] =
      *(const float4*)&kn[(size_t)(t0+rr)*KVC + kvh*HD + lc*4];
    *(float4*)&Vsh[rr*64 + sw] =
      *(const float4*)&vr[(size_t)(t0+rr)*KVC + kvh*HD + lc*4];
  }
  __syncthreads();

  float s[2][4];
  #pragma unroll
  for(int r=0;r<2;r++)
    #pragma unroll
    for(int c=0;c<4;c++) s[r][c] = -INFINITY;

  #pragma unroll
  for(int dg=0; dg<16; ++dg){
    floatx2 ka[4], kb[4];
    int ksw = ((dg ^ lc)&15)*4;
    #pragma unroll
    for(int c=0;c<4;c++){
      float4 kv = *(const float4*)&Ksh[(lc*4+c)*64 + ksw];
      ka[c] = (floatx2){kv.x, kv.y};
      kb[c] = (floatx2){kv.z, kv.w};
    }
    #pragma unroll
    for(int r=0;r<2;r++){
      float4 qv = *(const float4*)&QPsh[(w*8+lg*2+r)*68 + dg*4];
      floatx2 qa = (floatx2){qv.x, qv.y};
      floatx2 qb = (floatx2){qv.z, qv.w};
      #pragma unroll
      for(int c=0;c<4;c++){
        floatx2 sa = qa + ka[c];               // v_pk_add_f32
        floatx2 sb = qb + kb[c];
        s[r][c] = fmaxf(s[r][c],
                  fmaxf(fmaxf(sa.x, sa.y), fmaxf(sb.x, sb.y)));
      }
    }
  }

  float mrow[2], lrow[2];
  #pragma unroll
  for(int r=0;r<2;r++){
    int i = qs*32 + w*8 + lg*2 + r;
    #pragma unroll
    for(int c=0;c<4;c++)
      if (t0 + lc*4 + c > i) s[r][c] = -INFINITY;   // causal mask
    float mt = fmaxf(fmaxf(s[r][0],s[r][1]), fmaxf(s[r][2],s[r][3]));
    mt = fmaxf(mt, __shfl_xor(mt,1));
    mt = fmaxf(mt, __shfl_xor(mt,2));
    mt = fmaxf(mt, __shfl_xor(mt,4));
    mt = fmaxf(mt, __shfl_xor(mt,8));
    float p0 = __expf(s[r][0]-mt), p1 = __expf(s[r][1]-mt);
    float p2 = __expf(s[r][2]-mt), p3 = __expf(s[r][3]-mt);
    float ps = p0+p1+p2+p3;
    ps += __shfl_xor(ps,1); ps += __shfl_xor(ps,2);
    ps += __shfl_xor(ps,4); ps += __shfl_xor(ps,8);
    mrow[r] = mt; lrow[r] = ps;
    *(float4*)&QPsh[(w*8+lg*2+r)*68 + lc*4] = make_float4(p0,p1,p2,p3);
  }
  __builtin_amdgcn_wave_barrier();   // DS in-order per wave; rows wave-private

  floatx2 acc2[2][2];
  #pragma unroll
  for(int r=0;r<2;r++){
    acc2[r][0] = (floatx2){0.f,0.f};
    acc2[r][1] = (floatx2){0.f,0.f};
  }

  #pragma unroll
  for(int jg=0; jg<16; ++jg){
    floatx2 va[4], vb[4];
    int vsw = ((lc ^ jg)&15)*4;
    #pragma unroll
    for(int jj=0;jj<4;jj++){
      float4 vv = *(const float4*)&Vsh[(jg*4+jj)*64 + vsw];
      va[jj] = (floatx2){vv.x, vv.y};
      vb[jj] = (floatx2){vv.z, vv.w};
    }
    #pragma unroll
    for(int r=0;r<2;r++){
      float4 pv = *(const float4*)&QPsh[(w*8+lg*2+r)*68 + jg*4];
      #pragma unroll
      for(int jj=0;jj<4;jj++){
        float pj = (&pv.x)[jj];
        floatx2 pp = (floatx2){pj, pj};
        acc2[r][0] = __builtin_elementwise_fma(pp, va[jj], acc2[r][0]); // v_pk_fma_f32
        acc2[r][1] = __builtin_elementwise_fma(pp, vb[jj], acc2[r][1]);
      }
    }
  }

  #pragma unroll
  for(int r=0;r<2;r++){
    int i = qs*32 + w*8 + lg*2 + r;
    int pidx = (h*TT + i)*8 + ct;
    *(uint2*)&part_acc[(size_t)pidx*64 + lc*4] =
      make_uint2(pack_bf16(acc2[r][0].x, acc2[r][0].y),
                 pack_bf16(acc2[r][1].x, acc2[r][1].y));
    if (lc == 0) part_ml[pidx] = make_float2(mrow[r], lrow[r]);
  }
}

// ============================================================================
// K3: merge <=8 bf16 chunk partials per (h,row) -> yF bf16 A-fragments.
// (unchanged)
// ============================================================================
__global__ void __launch_bounds__(256) attn_reduce(const unsigned short* __restrict__ part_acc,
    const float2* __restrict__ part_ml, unsigned short* __restrict__ yF){
  int wid  = (blockIdx.x * blockDim.x + threadIdx.x) >> 6;  // 0..6143
  int lane = threadIdx.x & 63;
  int h = wid >> 9;
  int i = wid & 511;
  int nch = (i >> 6) + 1;       // wave-uniform
  int base = (h*TT + i)*8;

  float2 mls[8]; float acs[8];
  #pragma unroll
  for(int c=0;c<8;c++){
    mls[c] = part_ml[base + c];
    acs[c] = bf16_to_f32(part_acc[(size_t)(base + c)*64 + lane]);
  }

  float m = -INFINITY, l = 0.f, a = 0.f;
  #pragma unroll
  for(int c=0;c<8;c++){
    if (c < nch){
      float m_new = fmaxf(m, mls[c].x);
      float sa  = __expf(m - m_new);
      float sc_ = __expf(mls[c].x - m_new);
      l = l*sa + mls[c].y*sc_;
      a = a*sa + acs[c]*sc_;
      m = m_new;
    }
  }
  float val = a / l;
  int s = i>>4, rr = i&15;
  int ks = h*2 + (lane>>5), q2 = (lane>>3)&3, j = lane&7;
  yF[ (((size_t)(s*24 + ks)*64 + q2*16 + rr)<<3) + j ] = bf16_rn(val);
}

// ============================================================================
// K4: proj GEMM, fragment-direct, 192 blocks (8mt x 24 ntH of 32 cols).
// Round-13 change: 4-deep rotating register prefetch, fully unrolled so all
// register-array indices are compile-time (avoids scratch, covers ~2 full
// iterations of L2 latency instead of <1).
// ============================================================================
__global__ void __launch_bounds__(256) gemm_proj_mfma(
    const unsigned short* __restrict__ yF, const unsigned short* __restrict__ WpF,
    float* __restrict__ out){
  int bx = blockIdx.x;           // 0..191
  int mt = bx / 24, ntH = bx % 24;
  int tid = threadIdx.x, w = tid>>6, lane = tid&63, qq = lane>>4, r = lane&15;
  int s = mt*4 + w;   // 16-row strip

  const short8* Af = (const short8*)yF  + (size_t)s*24*64 + lane;
  const short8* Bf = (const short8*)WpF + lane;

  floatx4 acc[2];
  acc[0] = (floatx4){0.f,0.f,0.f,0.f};
  acc[1] = (floatx4){0.f,0.f,0.f,0.f};

  short8 ar[4]; short8 br[4][2];
  #pragma unroll
  for(int j=0;j<3;++j){
    ar[j] = Af[(size_t)j*64];
    #pragma unroll
    for(int c=0;c<2;c++) br[j][c] = Bf[(size_t)((ntH*2+c)*24 + j)*64];
  }

  #pragma unroll
  for(int ks=0; ks<24; ++ks){
    int cur = ks & 3;
    if (ks + 3 < 24){
      int nx = (ks+3) & 3;
      ar[nx] = Af[(size_t)(ks+3)*64];
      #pragma unroll
      for(int c=0;c<2;c++) br[nx][c] = Bf[(size_t)((ntH*2+c)*24 + ks+3)*64];
    }
    #pragma unroll
    for(int c=0;c<2;c++)
      acc[c] = __builtin_amdgcn_mfma_f32_16x16x32_bf16(ar[cur], br[cur][c], acc[c], 0,0,0);
  }

  #pragma unroll
  for(int reg=0; reg<4; ++reg){
    int t = mt*64 + w*16 + qq*4 + reg;
    float* dst = out + (size_t)t*CEMB + ntH*32;
    #pragma unroll
    for(int c=0;c<2;c++)
      dst[c*16 + r] = acc[c][reg];
  }
}

extern "C" void kernel_launch(void* const* d_in, const int* in_sizes, int n_in,
                              void* d_out, int out_size, void* d_ws, size_t ws_size,
                              hipStream_t stream){
  const float* x    = (const float*)d_in[0];
  const float* cosb = (const float*)d_in[1];
  const float* sinb = (const float*)d_in[2];
  const float* Wq   = (const float*)d_in[3];
  const float* Wk   = (const float*)d_in[4];
  const float* Wv   = (const float*)d_in[5];
  const float* Wp   = (const float*)d_in[6];
  float* out = (float*)d_out;

  float* ws        = (float*)d_ws;
  float* q_raw     = ws;                                // 512*768 f32
  float* k_raw     = q_raw + (size_t)TT*CEMB;           // 512*384 f32
  float* v_raw     = k_raw + (size_t)TT*KVC;            // 512*384 f32
  unsigned short* part_acc = (unsigned short*)(v_raw + (size_t)TT*KVC); // 12*512*8*64 bf16
  float2* part_ml  = (float2*)(part_acc + (size_t)NH*TT*8*64);          // 12*512*8
  unsigned short* WpF = (unsigned short*)(part_ml + (size_t)NH*TT*8);   // 48*24*64*8
  unsigned short* yF  = WpF + (size_t)48*24*64*8;       // 32*24*64*8

  gemm_qkv_mfma <<<dim3(228),   256, 0, stream>>>(x, Wq, Wk, Wv, Wp, cosb, sinb,
                                                  q_raw, k_raw, v_raw, WpF);
  attn_tile     <<<dim3(72,NH), 256, 0, stream>>>(q_raw, k_raw, v_raw, part_acc, part_ml);
  attn_reduce   <<<dim3(NH*TT/4), 256, 0, stream>>>(part_acc, part_ml, yF);
  gemm_proj_mfma<<<dim3(192),   256, 0, stream>>>(yF, WpF, out);
}